// Round 1
// baseline (1510.033 us; speedup 1.0000x reference)
//
#include <hip/hip_runtime.h>

#define N_FEAT   128
#define N_GRAPHS 2048
#define BN_EPS   1e-5f

// ---------------- scatter: agg[dst] += x[src]  (agg pre-initialized to x) ----
__global__ __launch_bounds__(256) void k_scatter(const float* __restrict__ x,
                                                 const int* __restrict__ src,
                                                 const int* __restrict__ dst,
                                                 float* __restrict__ agg,
                                                 int n_edges)
{
    long tid = (long)blockIdx.x * blockDim.x + threadIdx.x;
    int e = (int)(tid >> 5);          // 32 threads per edge
    if (e >= n_edges) return;
    int f4 = (int)(tid & 31);         // each thread: 4 consecutive floats
    int s = src[e], d = dst[e];
    float4 v = ((const float4*)(x + (size_t)s * N_FEAT))[f4];
    float* o = agg + (size_t)d * N_FEAT + f4 * 4;
    unsafeAtomicAdd(o + 0, v.x);
    unsafeAtomicAdd(o + 1, v.y);
    unsafeAtomicAdd(o + 2, v.z);
    unsafeAtomicAdd(o + 3, v.w);
}

// ---------------- fused MLP1: H = relu( relu(A@W1+b1) @ W2 + b2 ) ------------
// block: 256 threads, 32 rows x 128 cols tile; thread computes 4x4.
__global__ __launch_bounds__(256) void k_mlp1(const float* __restrict__ A,
                                              const float* __restrict__ W1,
                                              const float* __restrict__ b1,
                                              const float* __restrict__ W2,
                                              const float* __restrict__ b2,
                                              float* __restrict__ H,
                                              int n_rows)
{
    __shared__ float sA[32][128];   // 16 KB, reused for T1
    int t = threadIdx.x;
    int row0 = blockIdx.x * 32;

    // load A tile (zero-fill OOB rows)
    for (int i = t; i < 1024; i += 256) {
        int r = i >> 5, c = i & 31;
        int gr = row0 + r;
        float4 v = make_float4(0.f, 0.f, 0.f, 0.f);
        if (gr < n_rows) v = ((const float4*)(A + (size_t)gr * 128))[c];
        ((float4*)&sA[r][0])[c] = v;
    }
    __syncthreads();

    int tr = t >> 5, tc = t & 31;     // rows tr*4+i, cols tc*4+j
    int tr4 = tr * 4;
    float acc[4][4];
    #pragma unroll
    for (int i = 0; i < 4; i++)
        #pragma unroll
        for (int j = 0; j < 4; j++) acc[i][j] = 0.f;

    #pragma unroll 8
    for (int k = 0; k < 128; ++k) {
        float4 w = ((const float4*)(W1 + k * 128))[tc];
        #pragma unroll
        for (int i = 0; i < 4; i++) {
            float a = sA[tr4 + i][k];
            acc[i][0] = fmaf(a, w.x, acc[i][0]);
            acc[i][1] = fmaf(a, w.y, acc[i][1]);
            acc[i][2] = fmaf(a, w.z, acc[i][2]);
            acc[i][3] = fmaf(a, w.w, acc[i][3]);
        }
    }
    float4 bias1 = ((const float4*)b1)[tc];
    __syncthreads();   // all reads of sA done
    // T1 = relu(acc + b1) -> back into sA
    #pragma unroll
    for (int i = 0; i < 4; i++) {
        float4 o;
        o.x = fmaxf(acc[i][0] + bias1.x, 0.f);
        o.y = fmaxf(acc[i][1] + bias1.y, 0.f);
        o.z = fmaxf(acc[i][2] + bias1.z, 0.f);
        o.w = fmaxf(acc[i][3] + bias1.w, 0.f);
        ((float4*)&sA[tr4 + i][0])[tc] = o;
    }
    __syncthreads();

    #pragma unroll
    for (int i = 0; i < 4; i++)
        #pragma unroll
        for (int j = 0; j < 4; j++) acc[i][j] = 0.f;

    #pragma unroll 8
    for (int k = 0; k < 128; ++k) {
        float4 w = ((const float4*)(W2 + k * 128))[tc];
        #pragma unroll
        for (int i = 0; i < 4; i++) {
            float a = sA[tr4 + i][k];
            acc[i][0] = fmaf(a, w.x, acc[i][0]);
            acc[i][1] = fmaf(a, w.y, acc[i][1]);
            acc[i][2] = fmaf(a, w.z, acc[i][2]);
            acc[i][3] = fmaf(a, w.w, acc[i][3]);
        }
    }
    float4 bias2 = ((const float4*)b2)[tc];
    #pragma unroll
    for (int i = 0; i < 4; i++) {
        int gr = row0 + tr4 + i;
        if (gr < n_rows) {
            float4 o;
            o.x = fmaxf(acc[i][0] + bias2.x, 0.f);
            o.y = fmaxf(acc[i][1] + bias2.y, 0.f);
            o.z = fmaxf(acc[i][2] + bias2.z, 0.f);
            o.w = fmaxf(acc[i][3] + bias2.w, 0.f);
            ((float4*)(H + (size_t)gr * 128))[tc] = o;
        }
    }
}

// ---------------- BN stats: per-feature sum and sumsq -----------------------
__global__ __launch_bounds__(128) void k_bnstats(const float* __restrict__ H,
                                                 float* __restrict__ stats,
                                                 int n_rows)
{
    int f = threadIdx.x;
    float s = 0.f, s2 = 0.f;
    for (int r = blockIdx.x; r < n_rows; r += gridDim.x) {
        float v = H[(size_t)r * 128 + f];
        s += v;
        s2 += v * v;
    }
    unsafeAtomicAdd(&stats[f], s);
    unsafeAtomicAdd(&stats[128 + f], s2);
}

__global__ void k_bnfin(const float* __restrict__ stats,
                        const float* __restrict__ gamma,
                        const float* __restrict__ beta,
                        float* __restrict__ sc, int n_rows)
{
    int f = threadIdx.x;   // 128 threads
    float inv_n = 1.0f / (float)n_rows;
    float mean = stats[f] * inv_n;
    float var = stats[128 + f] * inv_n - mean * mean;
    float inv = rsqrtf(var + BN_EPS);
    float scale = gamma[f] * inv;
    sc[f] = scale;
    sc[128 + f] = beta[f] - mean * scale;
}

// ---------------- pool: g[batch[n]] += H[n]*scale + shift -------------------
__global__ __launch_bounds__(256) void k_pool(const float* __restrict__ H,
                                              const int* __restrict__ batch,
                                              const float* __restrict__ sc,
                                              float* __restrict__ g,
                                              int n_rows)
{
    int idx = blockIdx.x * 2 + (threadIdx.x >> 7);
    if (idx >= n_rows) return;
    int f = threadIdx.x & 127;
    int b = batch[idx];
    float v = H[(size_t)idx * 128 + f] * sc[f] + sc[128 + f];
    unsafeAtomicAdd(&g[(size_t)b * 128 + f], v);
}

// ---------------- head: out = relu(g@Wf1+bf1)@Wf2 + bf2 ---------------------
__global__ __launch_bounds__(256) void k_head(const float* __restrict__ g,
                                              const float* __restrict__ Wf1,
                                              const float* __restrict__ bf1,
                                              const float* __restrict__ Wf2,
                                              const float* __restrict__ bf2,
                                              float* __restrict__ out)
{
    __shared__ float sg[128];
    __shared__ float sh[256];
    int t = threadIdx.x;
    int G = blockIdx.x;
    if (t < 128) sg[t] = g[(size_t)G * 128 + t];
    __syncthreads();
    float a = bf1[t];
    #pragma unroll 8
    for (int k = 0; k < 128; ++k) a = fmaf(sg[k], Wf1[k * 256 + t], a);
    sh[t] = fmaxf(a, 0.f);
    __syncthreads();
    if (t < 192) {
        int o = t >> 4, l = t & 15;
        float p = 0.f;
        for (int k = l; k < 256; k += 16) p += sh[k] * Wf2[k * 12 + o];
        #pragma unroll
        for (int m = 8; m >= 1; m >>= 1) p += __shfl_xor(p, m, 16);
        if (l == 0) out[(size_t)G * 12 + o] = p + bf2[o];
    }
}

extern "C" void kernel_launch(void* const* d_in, const int* in_sizes, int n_in,
                              void* d_out, int out_size, void* d_ws, size_t ws_size,
                              hipStream_t stream)
{
    const float* x     = (const float*)d_in[0];
    const int*   ei    = (const int*)d_in[1];
    const int*   batch = (const int*)d_in[2];
    const float* W1    = (const float*)d_in[3];
    const float* b1    = (const float*)d_in[4];
    const float* W2    = (const float*)d_in[5];
    const float* b2    = (const float*)d_in[6];
    const float* gamma = (const float*)d_in[7];
    const float* beta  = (const float*)d_in[8];
    const float* Wf1   = (const float*)d_in[9];
    const float* bf1   = (const float*)d_in[10];
    const float* Wf2   = (const float*)d_in[11];
    const float* bf2   = (const float*)d_in[12];

    int n_nodes = in_sizes[0] / N_FEAT;
    int n_edges = in_sizes[1] / 2;
    const int* src = ei;
    const int* dst = ei + n_edges;

    char* ws = (char*)d_ws;
    size_t nodeBytes = (size_t)n_nodes * N_FEAT * sizeof(float);
    float* hsum  = (float*)ws;                                 // [N][128]
    float* H     = (float*)(ws + nodeBytes);                   // [N][128]
    float* g     = (float*)(ws + 2 * nodeBytes);               // [2048][128]
    size_t gBytes = (size_t)N_GRAPHS * N_FEAT * sizeof(float);
    float* stats = (float*)(ws + 2 * nodeBytes + gBytes);      // [256]
    float* sc    = stats + 256;                                // [256]

    // agg starts as x (folds the +x of GIN eps=0)
    hipMemcpyAsync(hsum, x, nodeBytes, hipMemcpyDeviceToDevice, stream);
    // zero g + stats + sc (contiguous)
    hipMemsetAsync(g, 0, gBytes + 512 * sizeof(float), stream);

    {
        long threads = (long)n_edges * 32;
        int blocks = (int)((threads + 255) / 256);
        k_scatter<<<blocks, 256, 0, stream>>>(x, src, dst, hsum, n_edges);
    }
    k_mlp1<<<(n_nodes + 31) / 32, 256, 0, stream>>>(hsum, W1, b1, W2, b2, H, n_nodes);
    k_bnstats<<<256, 128, 0, stream>>>(H, stats, n_nodes);
    k_bnfin<<<1, 128, 0, stream>>>(stats, gamma, beta, sc, n_nodes);
    k_pool<<<(n_nodes + 1) / 2, 256, 0, stream>>>(H, batch, sc, g, n_nodes);
    k_head<<<N_GRAPHS, 256, 0, stream>>>(g, Wf1, bf1, Wf2, bf2, (float*)d_out);
}

// Round 2
// 391.817 us; speedup vs baseline: 3.8539x; 3.8539x over previous
//
#include <hip/hip_runtime.h>

#define N_FEAT   128
#define N_GRAPHS 2048
#define BN_EPS   1e-5f

// ---------------- CSR build: histogram of dst -------------------------------
__global__ __launch_bounds__(256) void k_hist(const int* __restrict__ dst,
                                              int* __restrict__ counts,
                                              int n_edges)
{
    int e = blockIdx.x * 256 + threadIdx.x;
    if (e < n_edges) atomicAdd(&counts[dst[e]], 1);
}

// ---------------- CSR build: exclusive prefix scan (single block) -----------
__global__ __launch_bounds__(1024) void k_scan(const int* __restrict__ counts,
                                               int* __restrict__ row_start,
                                               int n)
{
    __shared__ int part[1024];
    int t = threadIdx.x;
    int per = (n + 1023) / 1024;
    int beg = t * per;
    int end = min(n, beg + per);
    int s = 0;
    for (int i = beg; i < end; ++i) s += counts[i];
    part[t] = s;
    __syncthreads();
    // inclusive Hillis-Steele scan over 1024 partials
    for (int off = 1; off < 1024; off <<= 1) {
        int v = (t >= off) ? part[t - off] : 0;
        __syncthreads();
        part[t] += v;
        __syncthreads();
    }
    int run = (t == 0) ? 0 : part[t - 1];
    for (int i = beg; i < end; ++i) { row_start[i] = run; run += counts[i]; }
    if (end == n) row_start[n] = run;   // total (same value from all writers)
}

// ---------------- CSR build: fill adjacency ---------------------------------
__global__ __launch_bounds__(256) void k_fill(const int* __restrict__ src,
                                              const int* __restrict__ dst,
                                              int* __restrict__ cursor,
                                              int* __restrict__ csr,
                                              int n_edges)
{
    int e = blockIdx.x * 256 + threadIdx.x;
    if (e < n_edges) {
        int slot = atomicAdd(&cursor[dst[e]], 1);
        csr[slot] = src[e];
    }
}

// ---------------- pull aggregation: agg[n] = x[n] + sum_j x[csr[j]] ---------
__global__ __launch_bounds__(256) void k_gather(const float* __restrict__ x,
                                                const int* __restrict__ csr,
                                                const int* __restrict__ row_start,
                                                float* __restrict__ agg,
                                                int n_nodes)
{
    int node = blockIdx.x * 8 + (threadIdx.x >> 5);   // 8 nodes/block, 32 lanes/node
    if (node >= n_nodes) return;
    int f4 = threadIdx.x & 31;
    int beg = row_start[node], end = row_start[node + 1];
    float4 v = ((const float4*)(x + (size_t)node * N_FEAT))[f4];
    for (int j = beg; j < end; ++j) {
        int s = csr[j];
        float4 u = ((const float4*)(x + (size_t)s * N_FEAT))[f4];
        v.x += u.x; v.y += u.y; v.z += u.z; v.w += u.w;
    }
    ((float4*)(agg + (size_t)node * N_FEAT))[f4] = v;
}

// ---------------- fused MLP1: H = relu( relu(A@W1+b1) @ W2 + b2 ) ------------
__global__ __launch_bounds__(256) void k_mlp1(const float* __restrict__ A,
                                              const float* __restrict__ W1,
                                              const float* __restrict__ b1,
                                              const float* __restrict__ W2,
                                              const float* __restrict__ b2,
                                              float* __restrict__ H,
                                              int n_rows)
{
    __shared__ float sA[32][128];   // 16 KB, reused for T1
    int t = threadIdx.x;
    int row0 = blockIdx.x * 32;

    for (int i = t; i < 1024; i += 256) {
        int r = i >> 5, c = i & 31;
        int gr = row0 + r;
        float4 v = make_float4(0.f, 0.f, 0.f, 0.f);
        if (gr < n_rows) v = ((const float4*)(A + (size_t)gr * 128))[c];
        ((float4*)&sA[r][0])[c] = v;
    }
    __syncthreads();

    int tr = t >> 5, tc = t & 31;
    int tr4 = tr * 4;
    float acc[4][4];
    #pragma unroll
    for (int i = 0; i < 4; i++)
        #pragma unroll
        for (int j = 0; j < 4; j++) acc[i][j] = 0.f;

    #pragma unroll 8
    for (int k = 0; k < 128; ++k) {
        float4 w = ((const float4*)(W1 + k * 128))[tc];
        #pragma unroll
        for (int i = 0; i < 4; i++) {
            float a = sA[tr4 + i][k];
            acc[i][0] = fmaf(a, w.x, acc[i][0]);
            acc[i][1] = fmaf(a, w.y, acc[i][1]);
            acc[i][2] = fmaf(a, w.z, acc[i][2]);
            acc[i][3] = fmaf(a, w.w, acc[i][3]);
        }
    }
    float4 bias1 = ((const float4*)b1)[tc];
    __syncthreads();
    #pragma unroll
    for (int i = 0; i < 4; i++) {
        float4 o;
        o.x = fmaxf(acc[i][0] + bias1.x, 0.f);
        o.y = fmaxf(acc[i][1] + bias1.y, 0.f);
        o.z = fmaxf(acc[i][2] + bias1.z, 0.f);
        o.w = fmaxf(acc[i][3] + bias1.w, 0.f);
        ((float4*)&sA[tr4 + i][0])[tc] = o;
    }
    __syncthreads();

    #pragma unroll
    for (int i = 0; i < 4; i++)
        #pragma unroll
        for (int j = 0; j < 4; j++) acc[i][j] = 0.f;

    #pragma unroll 8
    for (int k = 0; k < 128; ++k) {
        float4 w = ((const float4*)(W2 + k * 128))[tc];
        #pragma unroll
        for (int i = 0; i < 4; i++) {
            float a = sA[tr4 + i][k];
            acc[i][0] = fmaf(a, w.x, acc[i][0]);
            acc[i][1] = fmaf(a, w.y, acc[i][1]);
            acc[i][2] = fmaf(a, w.z, acc[i][2]);
            acc[i][3] = fmaf(a, w.w, acc[i][3]);
        }
    }
    float4 bias2 = ((const float4*)b2)[tc];
    #pragma unroll
    for (int i = 0; i < 4; i++) {
        int gr = row0 + tr4 + i;
        if (gr < n_rows) {
            float4 o;
            o.x = fmaxf(acc[i][0] + bias2.x, 0.f);
            o.y = fmaxf(acc[i][1] + bias2.y, 0.f);
            o.z = fmaxf(acc[i][2] + bias2.z, 0.f);
            o.w = fmaxf(acc[i][3] + bias2.w, 0.f);
            ((float4*)(H + (size_t)gr * 128))[tc] = o;
        }
    }
}

// ---------------- BN stats: per-feature sum and sumsq -----------------------
__global__ __launch_bounds__(128) void k_bnstats(const float* __restrict__ H,
                                                 float* __restrict__ stats,
                                                 int n_rows)
{
    int f = threadIdx.x;
    float s = 0.f, s2 = 0.f;
    for (int r = blockIdx.x; r < n_rows; r += gridDim.x) {
        float v = H[(size_t)r * 128 + f];
        s += v;
        s2 += v * v;
    }
    unsafeAtomicAdd(&stats[f], s);
    unsafeAtomicAdd(&stats[128 + f], s2);
}

__global__ void k_bnfin(const float* __restrict__ stats,
                        const float* __restrict__ gamma,
                        const float* __restrict__ beta,
                        float* __restrict__ sc, int n_rows)
{
    int f = threadIdx.x;   // 128 threads
    float inv_n = 1.0f / (float)n_rows;
    float mean = stats[f] * inv_n;
    float var = stats[128 + f] * inv_n - mean * mean;
    float inv = rsqrtf(var + BN_EPS);
    float scale = gamma[f] * inv;
    sc[f] = scale;
    sc[128 + f] = beta[f] - mean * scale;
}

// ---------------- pool: g[batch[n]] += H[n]*scale + shift -------------------
__global__ __launch_bounds__(256) void k_pool(const float* __restrict__ H,
                                              const int* __restrict__ batch,
                                              const float* __restrict__ sc,
                                              float* __restrict__ g,
                                              int n_rows)
{
    int idx = blockIdx.x * 2 + (threadIdx.x >> 7);
    if (idx >= n_rows) return;
    int f = threadIdx.x & 127;
    int b = batch[idx];
    float v = H[(size_t)idx * 128 + f] * sc[f] + sc[128 + f];
    unsafeAtomicAdd(&g[(size_t)b * 128 + f], v);
}

// ---------------- head: out = relu(g@Wf1+bf1)@Wf2 + bf2 ---------------------
__global__ __launch_bounds__(256) void k_head(const float* __restrict__ g,
                                              const float* __restrict__ Wf1,
                                              const float* __restrict__ bf1,
                                              const float* __restrict__ Wf2,
                                              const float* __restrict__ bf2,
                                              float* __restrict__ out)
{
    __shared__ float sg[128];
    __shared__ float sh[256];
    int t = threadIdx.x;
    int G = blockIdx.x;
    if (t < 128) sg[t] = g[(size_t)G * 128 + t];
    __syncthreads();
    float a = bf1[t];
    #pragma unroll 8
    for (int k = 0; k < 128; ++k) a = fmaf(sg[k], Wf1[k * 256 + t], a);
    sh[t] = fmaxf(a, 0.f);
    __syncthreads();
    if (t < 192) {
        int o = t >> 4, l = t & 15;
        float p = 0.f;
        for (int k = l; k < 256; k += 16) p += sh[k] * Wf2[k * 12 + o];
        #pragma unroll
        for (int m = 8; m >= 1; m >>= 1) p += __shfl_xor(p, m, 16);
        if (l == 0) out[(size_t)G * 12 + o] = p + bf2[o];
    }
}

extern "C" void kernel_launch(void* const* d_in, const int* in_sizes, int n_in,
                              void* d_out, int out_size, void* d_ws, size_t ws_size,
                              hipStream_t stream)
{
    const float* x     = (const float*)d_in[0];
    const int*   ei    = (const int*)d_in[1];
    const int*   batch = (const int*)d_in[2];
    const float* W1    = (const float*)d_in[3];
    const float* b1    = (const float*)d_in[4];
    const float* W2    = (const float*)d_in[5];
    const float* b2    = (const float*)d_in[6];
    const float* gamma = (const float*)d_in[7];
    const float* beta  = (const float*)d_in[8];
    const float* Wf1   = (const float*)d_in[9];
    const float* bf1   = (const float*)d_in[10];
    const float* Wf2   = (const float*)d_in[11];
    const float* bf2   = (const float*)d_in[12];

    int n_nodes = in_sizes[0] / N_FEAT;
    int n_edges = in_sizes[1] / 2;
    const int* src = ei;
    const int* dst = ei + n_edges;

    char* ws = (char*)d_ws;
    size_t nodeBytes = (size_t)n_nodes * N_FEAT * sizeof(float);
    size_t gBytes = (size_t)N_GRAPHS * N_FEAT * sizeof(float);
    float* hsum  = (float*)ws;                                  // [N][128]
    float* H     = (float*)(ws + nodeBytes);                    // [N][128]
    float* g     = (float*)(ws + 2 * nodeBytes);                // [2048][128]
    float* stats = (float*)(ws + 2 * nodeBytes + gBytes);       // [256]
    float* sc    = stats + 256;                                 // [256]
    char*  p     = (char*)(sc + 256);
    int* counts    = (int*)p;                 p += (size_t)n_nodes * sizeof(int);
    int* row_start = (int*)p;                 p += (size_t)(n_nodes + 1) * sizeof(int);
    int* cursor    = (int*)p;                 p += (size_t)n_nodes * sizeof(int);
    int* csr       = (int*)p;                 // [n_edges]

    // zero: g + stats + sc (contiguous), counts
    hipMemsetAsync(g, 0, gBytes + 512 * sizeof(float), stream);
    hipMemsetAsync(counts, 0, (size_t)n_nodes * sizeof(int), stream);

    // ---- CSR build ----
    int eb = (n_edges + 255) / 256;
    k_hist<<<eb, 256, 0, stream>>>(dst, counts, n_edges);
    k_scan<<<1, 1024, 0, stream>>>(counts, row_start, n_nodes);
    hipMemcpyAsync(cursor, row_start, (size_t)n_nodes * sizeof(int),
                   hipMemcpyDeviceToDevice, stream);
    k_fill<<<eb, 256, 0, stream>>>(src, dst, cursor, csr, n_edges);

    // ---- pull aggregation (includes +x) ----
    k_gather<<<(n_nodes + 7) / 8, 256, 0, stream>>>(x, csr, row_start, hsum, n_nodes);

    // ---- rest of the net ----
    k_mlp1<<<(n_nodes + 31) / 32, 256, 0, stream>>>(hsum, W1, b1, W2, b2, H, n_nodes);
    k_bnstats<<<256, 128, 0, stream>>>(H, stats, n_nodes);
    k_bnfin<<<1, 128, 0, stream>>>(stats, gamma, beta, sc, n_nodes);
    k_pool<<<(n_nodes + 1) / 2, 256, 0, stream>>>(H, batch, sc, g, n_nodes);
    k_head<<<N_GRAPHS, 256, 0, stream>>>(g, Wf1, bf1, Wf2, bf2, (float*)d_out);
}

// Round 3
// 306.748 us; speedup vs baseline: 4.9227x; 1.2773x over previous
//
#include <hip/hip_runtime.h>

#define N_FEAT   128
#define N_GRAPHS 2048
#define BN_EPS   1e-5f

// ---------------- CSR build: histogram of dst -------------------------------
__global__ __launch_bounds__(256) void k_hist(const int* __restrict__ dst,
                                              int* __restrict__ counts,
                                              int n_edges)
{
    int e = blockIdx.x * 256 + threadIdx.x;
    if (e < n_edges) atomicAdd(&counts[dst[e]], 1);
}

// ---------------- hierarchical exclusive scan over counts -------------------
// pass 1: per-block (256-elem) sums
__global__ __launch_bounds__(256) void k_bsum(const int* __restrict__ counts,
                                              int* __restrict__ bsum, int n)
{
    __shared__ int s[256];
    int t = threadIdx.x;
    int i = blockIdx.x * 256 + t;
    s[t] = (i < n) ? counts[i] : 0;
    __syncthreads();
    for (int o = 128; o > 0; o >>= 1) {
        if (t < o) s[t] += s[t + o];
        __syncthreads();
    }
    if (t == 0) bsum[blockIdx.x] = s[0];
}

// pass 2: exclusive scan of block sums (nb <= 256), single block
__global__ __launch_bounds__(256) void k_bscan(const int* __restrict__ bsum,
                                               int* __restrict__ boff, int nb)
{
    __shared__ int s[256];
    int t = threadIdx.x;
    int v = (t < nb) ? bsum[t] : 0;
    s[t] = v;
    __syncthreads();
    for (int o = 1; o < 256; o <<= 1) {
        int u = (t >= o) ? s[t - o] : 0;
        __syncthreads();
        s[t] += u;
        __syncthreads();
    }
    boff[t] = s[t] - v;   // exclusive
}

// pass 3: block-local scan + offset; writes row_start AND cursor
__global__ __launch_bounds__(256) void k_apply(const int* __restrict__ counts,
                                               const int* __restrict__ boff,
                                               int* __restrict__ row_start,
                                               int* __restrict__ cursor, int n)
{
    __shared__ int s[256];
    int t = threadIdx.x;
    int i = blockIdx.x * 256 + t;
    int c = (i < n) ? counts[i] : 0;
    s[t] = c;
    __syncthreads();
    for (int o = 1; o < 256; o <<= 1) {
        int u = (t >= o) ? s[t - o] : 0;
        __syncthreads();
        s[t] += u;
        __syncthreads();
    }
    int excl = boff[blockIdx.x] + s[t] - c;
    if (i < n) {
        row_start[i] = excl;
        cursor[i] = excl;
        if (i == n - 1) row_start[n] = excl + c;
    }
}

// ---------------- CSR build: fill adjacency ---------------------------------
__global__ __launch_bounds__(256) void k_fill(const int* __restrict__ src,
                                              const int* __restrict__ dst,
                                              int* __restrict__ cursor,
                                              int* __restrict__ csr,
                                              int n_edges)
{
    int e = blockIdx.x * 256 + threadIdx.x;
    if (e < n_edges) {
        int slot = atomicAdd(&cursor[dst[e]], 1);
        csr[slot] = src[e];
    }
}

// ---------------- pull aggregation: agg[n] = x[n] + sum_j x[csr[j]] ---------
// one node per wave (64 lanes x float2); edge loop is wave-uniform
__global__ __launch_bounds__(256) void k_gather(const float* __restrict__ x,
                                                const int* __restrict__ csr,
                                                const int* __restrict__ row_start,
                                                float* __restrict__ agg,
                                                int n_nodes)
{
    int node = blockIdx.x * 4 + (threadIdx.x >> 6);
    if (node >= n_nodes) return;
    int l = threadIdx.x & 63;
    const float2* xr = (const float2*)x;
    float2 v = xr[(size_t)node * 64 + l];
    int beg = row_start[node], end = row_start[node + 1];
    int j = beg;
    for (; j + 1 < end; j += 2) {
        int s0 = csr[j], s1 = csr[j + 1];
        float2 u0 = xr[(size_t)s0 * 64 + l];
        float2 u1 = xr[(size_t)s1 * 64 + l];
        v.x += u0.x + u1.x;
        v.y += u0.y + u1.y;
    }
    if (j < end) {
        float2 u = xr[(size_t)csr[j] * 64 + l];
        v.x += u.x;
        v.y += u.y;
    }
    ((float2*)agg)[(size_t)node * 64 + l] = v;
}

// ---------------- fused MLP1: H = relu( relu(A@W1+b1) @ W2 + b2 ) ------------
__global__ __launch_bounds__(256) void k_mlp1(const float* __restrict__ A,
                                              const float* __restrict__ W1,
                                              const float* __restrict__ b1,
                                              const float* __restrict__ W2,
                                              const float* __restrict__ b2,
                                              float* __restrict__ H,
                                              int n_rows)
{
    __shared__ float sA[32][128];   // 16 KB, reused for T1
    int t = threadIdx.x;
    int row0 = blockIdx.x * 32;

    for (int i = t; i < 1024; i += 256) {
        int r = i >> 5, c = i & 31;
        int gr = row0 + r;
        float4 v = make_float4(0.f, 0.f, 0.f, 0.f);
        if (gr < n_rows) v = ((const float4*)(A + (size_t)gr * 128))[c];
        ((float4*)&sA[r][0])[c] = v;
    }
    __syncthreads();

    int tr = t >> 5, tc = t & 31;
    int tr4 = tr * 4;
    float acc[4][4];
    #pragma unroll
    for (int i = 0; i < 4; i++)
        #pragma unroll
        for (int j = 0; j < 4; j++) acc[i][j] = 0.f;

    #pragma unroll 8
    for (int k = 0; k < 128; ++k) {
        float4 w = ((const float4*)(W1 + k * 128))[tc];
        #pragma unroll
        for (int i = 0; i < 4; i++) {
            float a = sA[tr4 + i][k];
            acc[i][0] = fmaf(a, w.x, acc[i][0]);
            acc[i][1] = fmaf(a, w.y, acc[i][1]);
            acc[i][2] = fmaf(a, w.z, acc[i][2]);
            acc[i][3] = fmaf(a, w.w, acc[i][3]);
        }
    }
    float4 bias1 = ((const float4*)b1)[tc];
    __syncthreads();
    #pragma unroll
    for (int i = 0; i < 4; i++) {
        float4 o;
        o.x = fmaxf(acc[i][0] + bias1.x, 0.f);
        o.y = fmaxf(acc[i][1] + bias1.y, 0.f);
        o.z = fmaxf(acc[i][2] + bias1.z, 0.f);
        o.w = fmaxf(acc[i][3] + bias1.w, 0.f);
        ((float4*)&sA[tr4 + i][0])[tc] = o;
    }
    __syncthreads();

    #pragma unroll
    for (int i = 0; i < 4; i++)
        #pragma unroll
        for (int j = 0; j < 4; j++) acc[i][j] = 0.f;

    #pragma unroll 8
    for (int k = 0; k < 128; ++k) {
        float4 w = ((const float4*)(W2 + k * 128))[tc];
        #pragma unroll
        for (int i = 0; i < 4; i++) {
            float a = sA[tr4 + i][k];
            acc[i][0] = fmaf(a, w.x, acc[i][0]);
            acc[i][1] = fmaf(a, w.y, acc[i][1]);
            acc[i][2] = fmaf(a, w.z, acc[i][2]);
            acc[i][3] = fmaf(a, w.w, acc[i][3]);
        }
    }
    float4 bias2 = ((const float4*)b2)[tc];
    #pragma unroll
    for (int i = 0; i < 4; i++) {
        int gr = row0 + tr4 + i;
        if (gr < n_rows) {
            float4 o;
            o.x = fmaxf(acc[i][0] + bias2.x, 0.f);
            o.y = fmaxf(acc[i][1] + bias2.y, 0.f);
            o.z = fmaxf(acc[i][2] + bias2.z, 0.f);
            o.w = fmaxf(acc[i][3] + bias2.w, 0.f);
            ((float4*)(H + (size_t)gr * 128))[tc] = o;
        }
    }
}

// ---------------- BN stats: per-feature sum and sumsq -----------------------
__global__ __launch_bounds__(128) void k_bnstats(const float* __restrict__ H,
                                                 float* __restrict__ stats,
                                                 int n_rows)
{
    int f = threadIdx.x;
    float s = 0.f, s2 = 0.f;
    for (int r = blockIdx.x; r < n_rows; r += gridDim.x) {
        float v = H[(size_t)r * 128 + f];
        s += v;
        s2 += v * v;
    }
    unsafeAtomicAdd(&stats[f], s);
    unsafeAtomicAdd(&stats[128 + f], s2);
}

__global__ void k_bnfin(const float* __restrict__ stats,
                        const float* __restrict__ gamma,
                        const float* __restrict__ beta,
                        float* __restrict__ sc, int n_rows)
{
    int f = threadIdx.x;   // 128 threads
    float inv_n = 1.0f / (float)n_rows;
    float mean = stats[f] * inv_n;
    float var = stats[128 + f] * inv_n - mean * mean;
    float inv = rsqrtf(var + BN_EPS);
    float scale = gamma[f] * inv;
    sc[f] = scale;
    sc[128 + f] = beta[f] - mean * scale;
}

// ---------------- pool: g[batch[n]] += H[n]*scale + shift -------------------
__global__ __launch_bounds__(256) void k_pool(const float* __restrict__ H,
                                              const int* __restrict__ batch,
                                              const float* __restrict__ sc,
                                              float* __restrict__ g,
                                              int n_rows)
{
    int idx = blockIdx.x * 2 + (threadIdx.x >> 7);
    if (idx >= n_rows) return;
    int f = threadIdx.x & 127;
    int b = batch[idx];
    float v = H[(size_t)idx * 128 + f] * sc[f] + sc[128 + f];
    unsafeAtomicAdd(&g[(size_t)b * 128 + f], v);
}

// ---------------- head: out = relu(g@Wf1+bf1)@Wf2 + bf2 ---------------------
__global__ __launch_bounds__(256) void k_head(const float* __restrict__ g,
                                              const float* __restrict__ Wf1,
                                              const float* __restrict__ bf1,
                                              const float* __restrict__ Wf2,
                                              const float* __restrict__ bf2,
                                              float* __restrict__ out)
{
    __shared__ float sg[128];
    __shared__ float sh[256];
    int t = threadIdx.x;
    int G = blockIdx.x;
    if (t < 128) sg[t] = g[(size_t)G * 128 + t];
    __syncthreads();
    float a = bf1[t];
    #pragma unroll 8
    for (int k = 0; k < 128; ++k) a = fmaf(sg[k], Wf1[k * 256 + t], a);
    sh[t] = fmaxf(a, 0.f);
    __syncthreads();
    if (t < 192) {
        int o = t >> 4, l = t & 15;
        float p = 0.f;
        for (int k = l; k < 256; k += 16) p += sh[k] * Wf2[k * 12 + o];
        #pragma unroll
        for (int m = 8; m >= 1; m >>= 1) p += __shfl_xor(p, m, 16);
        if (l == 0) out[(size_t)G * 12 + o] = p + bf2[o];
    }
}

extern "C" void kernel_launch(void* const* d_in, const int* in_sizes, int n_in,
                              void* d_out, int out_size, void* d_ws, size_t ws_size,
                              hipStream_t stream)
{
    const float* x     = (const float*)d_in[0];
    const int*   ei    = (const int*)d_in[1];
    const int*   batch = (const int*)d_in[2];
    const float* W1    = (const float*)d_in[3];
    const float* b1    = (const float*)d_in[4];
    const float* W2    = (const float*)d_in[5];
    const float* b2    = (const float*)d_in[6];
    const float* gamma = (const float*)d_in[7];
    const float* beta  = (const float*)d_in[8];
    const float* Wf1   = (const float*)d_in[9];
    const float* bf1   = (const float*)d_in[10];
    const float* Wf2   = (const float*)d_in[11];
    const float* bf2   = (const float*)d_in[12];

    int n_nodes = in_sizes[0] / N_FEAT;
    int n_edges = in_sizes[1] / 2;
    const int* src = ei;
    const int* dst = ei + n_edges;

    char* ws = (char*)d_ws;
    size_t nodeBytes = (size_t)n_nodes * N_FEAT * sizeof(float);
    size_t gBytes = (size_t)N_GRAPHS * N_FEAT * sizeof(float);
    float* hsum  = (float*)ws;                                  // [N][128]
    float* H     = (float*)(ws + nodeBytes);                    // [N][128]
    float* g     = (float*)(ws + 2 * nodeBytes);                // [2048][128]
    float* stats = (float*)(ws + 2 * nodeBytes + gBytes);       // [256]
    float* sc    = stats + 256;                                 // [256]
    char*  p     = (char*)(sc + 256);
    int nb = (n_nodes + 255) / 256;                             // scan blocks (<=256)
    int* counts    = (int*)p;                 p += (size_t)n_nodes * sizeof(int);
    int* row_start = (int*)p;                 p += (size_t)(n_nodes + 1) * sizeof(int);
    int* cursor    = (int*)p;                 p += (size_t)n_nodes * sizeof(int);
    int* bsum      = (int*)p;                 p += 256 * sizeof(int);
    int* boff      = (int*)p;                 p += 256 * sizeof(int);
    int* csr       = (int*)p;                 // [n_edges]

    // zero: g + stats + sc (contiguous), counts
    hipMemsetAsync(g, 0, gBytes + 512 * sizeof(float), stream);
    hipMemsetAsync(counts, 0, (size_t)n_nodes * sizeof(int), stream);

    // ---- CSR build ----
    int eb = (n_edges + 255) / 256;
    k_hist<<<eb, 256, 0, stream>>>(dst, counts, n_edges);
    k_bsum<<<nb, 256, 0, stream>>>(counts, bsum, n_nodes);
    k_bscan<<<1, 256, 0, stream>>>(bsum, boff, nb);
    k_apply<<<nb, 256, 0, stream>>>(counts, boff, row_start, cursor, n_nodes);
    k_fill<<<eb, 256, 0, stream>>>(src, dst, cursor, csr, n_edges);

    // ---- pull aggregation (includes +x) ----
    k_gather<<<(n_nodes + 3) / 4, 256, 0, stream>>>(x, csr, row_start, hsum, n_nodes);

    // ---- rest of the net ----
    k_mlp1<<<(n_nodes + 31) / 32, 256, 0, stream>>>(hsum, W1, b1, W2, b2, H, n_nodes);
    k_bnstats<<<784, 128, 0, stream>>>(H, stats, n_nodes);
    k_bnfin<<<1, 128, 0, stream>>>(stats, gamma, beta, sc, n_nodes);
    k_pool<<<(n_nodes + 1) / 2, 256, 0, stream>>>(H, batch, sc, g, n_nodes);
    k_head<<<N_GRAPHS, 256, 0, stream>>>(g, Wf1, bf1, Wf2, bf2, (float*)d_out);
}

// Round 4
// 256.701 us; speedup vs baseline: 5.8825x; 1.1950x over previous
//
#include <hip/hip_runtime.h>

#define N_FEAT   128
#define N_GRAPHS 2048
#define BN_EPS   1e-5f
#define LDA      136   // padded LDS row length (bf16 elems): +8 pad -> 2-way bank alias (free)

typedef __attribute__((ext_vector_type(8))) short  bf16x8;
typedef __attribute__((ext_vector_type(4))) float  f32x4;

__device__ __forceinline__ unsigned short f2bf(float f) {
    union { float f; unsigned int u; } c; c.f = f;
    unsigned int r = c.u + 0x7fffu + ((c.u >> 16) & 1u);   // RNE
    return (unsigned short)(r >> 16);
}
__device__ __forceinline__ float bf2f(unsigned short h) {
    union { unsigned int u; float f; } c; c.u = ((unsigned int)h) << 16;
    return c.f;
}

// ---------------- CSR build: histogram of dst -------------------------------
__global__ __launch_bounds__(256) void k_hist(const int* __restrict__ dst,
                                              int* __restrict__ counts,
                                              int n_edges)
{
    int e = blockIdx.x * 256 + threadIdx.x;
    if (e < n_edges) atomicAdd(&counts[dst[e]], 1);
}

// ---------------- hierarchical exclusive scan over counts -------------------
__global__ __launch_bounds__(256) void k_bsum(const int* __restrict__ counts,
                                              int* __restrict__ bsum, int n)
{
    __shared__ int s[256];
    int t = threadIdx.x;
    int i = blockIdx.x * 256 + t;
    s[t] = (i < n) ? counts[i] : 0;
    __syncthreads();
    for (int o = 128; o > 0; o >>= 1) {
        if (t < o) s[t] += s[t + o];
        __syncthreads();
    }
    if (t == 0) bsum[blockIdx.x] = s[0];
}

__global__ __launch_bounds__(256) void k_bscan(const int* __restrict__ bsum,
                                               int* __restrict__ boff, int nb)
{
    __shared__ int s[256];
    int t = threadIdx.x;
    int v = (t < nb) ? bsum[t] : 0;
    s[t] = v;
    __syncthreads();
    for (int o = 1; o < 256; o <<= 1) {
        int u = (t >= o) ? s[t - o] : 0;
        __syncthreads();
        s[t] += u;
        __syncthreads();
    }
    boff[t] = s[t] - v;   // exclusive
}

__global__ __launch_bounds__(256) void k_apply(const int* __restrict__ counts,
                                               const int* __restrict__ boff,
                                               int* __restrict__ row_start,
                                               int* __restrict__ cursor, int n)
{
    __shared__ int s[256];
    int t = threadIdx.x;
    int i = blockIdx.x * 256 + t;
    int c = (i < n) ? counts[i] : 0;
    s[t] = c;
    __syncthreads();
    for (int o = 1; o < 256; o <<= 1) {
        int u = (t >= o) ? s[t - o] : 0;
        __syncthreads();
        s[t] += u;
        __syncthreads();
    }
    int excl = boff[blockIdx.x] + s[t] - c;
    if (i < n) {
        row_start[i] = excl;
        cursor[i] = excl;
        if (i == n - 1) row_start[n] = excl + c;
    }
}

// ---------------- CSR build: fill adjacency ---------------------------------
__global__ __launch_bounds__(256) void k_fill(const int* __restrict__ src,
                                              const int* __restrict__ dst,
                                              int* __restrict__ cursor,
                                              int* __restrict__ csr,
                                              int n_edges)
{
    int e = blockIdx.x * 256 + threadIdx.x;
    if (e < n_edges) {
        int slot = atomicAdd(&cursor[dst[e]], 1);
        csr[slot] = src[e];
    }
}

// ---------------- weight prep: Wt[c][k] = bf16(W[k][c]) ---------------------
__global__ __launch_bounds__(256) void k_cvtW(const float* __restrict__ W1,
                                              const float* __restrict__ W2,
                                              unsigned short* __restrict__ Wt1,
                                              unsigned short* __restrict__ Wt2)
{
    int i = blockIdx.x * 256 + threadIdx.x;   // 0..32767
    int which = i >> 14;
    int k = (i >> 7) & 127;
    int c = i & 127;
    const float* W = which ? W2 : W1;
    unsigned short* O = which ? Wt2 : Wt1;
    O[c * 128 + k] = f2bf(W[k * 128 + c]);
}

// ---------------- pull aggregation -> split bf16 hi/lo planes ---------------
__global__ __launch_bounds__(256) void k_gather(const float* __restrict__ x,
                                                const int* __restrict__ csr,
                                                const int* __restrict__ row_start,
                                                unsigned short* __restrict__ Ahi,
                                                unsigned short* __restrict__ Alo,
                                                int n_nodes)
{
    int node = blockIdx.x * 4 + (threadIdx.x >> 6);
    if (node >= n_nodes) return;
    int l = threadIdx.x & 63;
    const float2* xr = (const float2*)x;
    float2 v = xr[(size_t)node * 64 + l];
    int beg = row_start[node], end = row_start[node + 1];
    int j = beg;
    for (; j + 1 < end; j += 2) {
        int s0 = csr[j], s1 = csr[j + 1];
        float2 u0 = xr[(size_t)s0 * 64 + l];
        float2 u1 = xr[(size_t)s1 * 64 + l];
        v.x += u0.x + u1.x;
        v.y += u0.y + u1.y;
    }
    if (j < end) {
        float2 u = xr[(size_t)csr[j] * 64 + l];
        v.x += u.x;
        v.y += u.y;
    }
    ushort2 h2, l2;
    h2.x = f2bf(v.x); l2.x = f2bf(v.x - bf2f(h2.x));
    h2.y = f2bf(v.y); l2.y = f2bf(v.y - bf2f(h2.y));
    ((ushort2*)Ahi)[(size_t)node * 64 + l] = h2;
    ((ushort2*)Alo)[(size_t)node * 64 + l] = l2;
}

// ---------------- fused MLP1 via MFMA (split-bf16 A, bf16 W, f32 acc) -------
// block: 256 thr = 4 waves; tile 64 rows x 128 cols; wave w -> cols w*32..+31.
// Per wave: 4 m-frags x 2 n-frags x 4 k-steps, 2 MFMA (hi/lo) each.
__global__ __launch_bounds__(256) void k_mlp1_mfma(const unsigned short* __restrict__ Ahi,
                                                   const unsigned short* __restrict__ Alo,
                                                   const unsigned short* __restrict__ Wt1,
                                                   const float* __restrict__ b1,
                                                   const unsigned short* __restrict__ Wt2,
                                                   const float* __restrict__ b2,
                                                   float* __restrict__ H,
                                                   int n_rows)
{
    __shared__ unsigned short sHi[64 * LDA];
    __shared__ unsigned short sLo[64 * LDA];
    int t = threadIdx.x;
    int wave = t >> 6, l = t & 63;
    int lr = l & 15;        // row-part (A) / col-part (B,D)
    int lk = l >> 4;        // k-group 0..3
    int row0 = blockIdx.x * 64;
    int col0 = wave * 32;

    // stage A hi/lo tile: 64 rows x 128 bf16 per plane
    #pragma unroll
    for (int it = 0; it < 4; ++it) {
        int idx = it * 256 + t;          // 0..1023
        int r = idx >> 4, c8 = idx & 15;
        int gr = row0 + r;
        int4 vh = make_int4(0, 0, 0, 0), vl = make_int4(0, 0, 0, 0);
        if (gr < n_rows) {
            vh = ((const int4*)(Ahi + (size_t)gr * 128))[c8];
            vl = ((const int4*)(Alo + (size_t)gr * 128))[c8];
        }
        *(int4*)&sHi[r * LDA + c8 * 8] = vh;
        *(int4*)&sLo[r * LDA + c8 * 8] = vl;
    }
    __syncthreads();

    f32x4 acc[4][2];
    #pragma unroll
    for (int m = 0; m < 4; ++m)
        #pragma unroll
        for (int n = 0; n < 2; ++n) acc[m][n] = (f32x4){0.f, 0.f, 0.f, 0.f};

    // ---- layer 1: acc = A @ W1 ----
    #pragma unroll
    for (int ks = 0; ks < 4; ++ks) {
        bf16x8 bfrag[2];
        #pragma unroll
        for (int n = 0; n < 2; ++n) {
            int c = col0 + n * 16 + lr;
            bfrag[n] = *(const bf16x8*)(Wt1 + (size_t)c * 128 + ks * 32 + lk * 8);
        }
        #pragma unroll
        for (int m = 0; m < 4; ++m) {
            bf16x8 ah = *(const bf16x8*)&sHi[(m * 16 + lr) * LDA + ks * 32 + lk * 8];
            bf16x8 al = *(const bf16x8*)&sLo[(m * 16 + lr) * LDA + ks * 32 + lk * 8];
            #pragma unroll
            for (int n = 0; n < 2; ++n) {
                acc[m][n] = __builtin_amdgcn_mfma_f32_16x16x32_bf16(ah, bfrag[n], acc[m][n], 0, 0, 0);
                acc[m][n] = __builtin_amdgcn_mfma_f32_16x16x32_bf16(al, bfrag[n], acc[m][n], 0, 0, 0);
            }
        }
    }
    __syncthreads();   // all waves done reading A tiles

    // ---- T1 = relu(acc + b1), split hi/lo back into sHi/sLo ----
    #pragma unroll
    for (int n = 0; n < 2; ++n) {
        int c = col0 + n * 16 + lr;
        float bb = b1[c];
        #pragma unroll
        for (int m = 0; m < 4; ++m) {
            #pragma unroll
            for (int i = 0; i < 4; ++i) {
                int r = m * 16 + lk * 4 + i;
                float v = fmaxf(acc[m][n][i] + bb, 0.f);
                unsigned short hb = f2bf(v);
                sHi[r * LDA + c] = hb;
                sLo[r * LDA + c] = f2bf(v - bf2f(hb));
            }
        }
    }
    __syncthreads();

    #pragma unroll
    for (int m = 0; m < 4; ++m)
        #pragma unroll
        for (int n = 0; n < 2; ++n) acc[m][n] = (f32x4){0.f, 0.f, 0.f, 0.f};

    // ---- layer 2: acc = T1 @ W2 ----
    #pragma unroll
    for (int ks = 0; ks < 4; ++ks) {
        bf16x8 bfrag[2];
        #pragma unroll
        for (int n = 0; n < 2; ++n) {
            int c = col0 + n * 16 + lr;
            bfrag[n] = *(const bf16x8*)(Wt2 + (size_t)c * 128 + ks * 32 + lk * 8);
        }
        #pragma unroll
        for (int m = 0; m < 4; ++m) {
            bf16x8 ah = *(const bf16x8*)&sHi[(m * 16 + lr) * LDA + ks * 32 + lk * 8];
            bf16x8 al = *(const bf16x8*)&sLo[(m * 16 + lr) * LDA + ks * 32 + lk * 8];
            #pragma unroll
            for (int n = 0; n < 2; ++n) {
                acc[m][n] = __builtin_amdgcn_mfma_f32_16x16x32_bf16(ah, bfrag[n], acc[m][n], 0, 0, 0);
                acc[m][n] = __builtin_amdgcn_mfma_f32_16x16x32_bf16(al, bfrag[n], acc[m][n], 0, 0, 0);
            }
        }
    }

    // ---- H = relu(acc + b2), f32 ----
    #pragma unroll
    for (int n = 0; n < 2; ++n) {
        int c = col0 + n * 16 + lr;
        float bb = b2[c];
        #pragma unroll
        for (int m = 0; m < 4; ++m) {
            #pragma unroll
            for (int i = 0; i < 4; ++i) {
                int gr = row0 + m * 16 + lk * 4 + i;
                if (gr < n_rows)
                    H[(size_t)gr * 128 + c] = fmaxf(acc[m][n][i] + bb, 0.f);
            }
        }
    }
}

// ---------------- BN stats: per-feature sum and sumsq -----------------------
__global__ __launch_bounds__(128) void k_bnstats(const float* __restrict__ H,
                                                 float* __restrict__ stats,
                                                 int n_rows)
{
    int f = threadIdx.x;
    float s = 0.f, s2 = 0.f;
    for (int r = blockIdx.x; r < n_rows; r += gridDim.x) {
        float v = H[(size_t)r * 128 + f];
        s += v;
        s2 += v * v;
    }
    unsafeAtomicAdd(&stats[f], s);
    unsafeAtomicAdd(&stats[128 + f], s2);
}

__global__ void k_bnfin(const float* __restrict__ stats,
                        const float* __restrict__ gamma,
                        const float* __restrict__ beta,
                        float* __restrict__ sc, int n_rows)
{
    int f = threadIdx.x;   // 128 threads
    float inv_n = 1.0f / (float)n_rows;
    float mean = stats[f] * inv_n;
    float var = stats[128 + f] * inv_n - mean * mean;
    float inv = rsqrtf(var + BN_EPS);
    float scale = gamma[f] * inv;
    sc[f] = scale;
    sc[128 + f] = beta[f] - mean * scale;
}

// ---------------- pool: g[batch[n]] += H[n]*scale + shift -------------------
__global__ __launch_bounds__(256) void k_pool(const float* __restrict__ H,
                                              const int* __restrict__ batch,
                                              const float* __restrict__ sc,
                                              float* __restrict__ g,
                                              int n_rows)
{
    int idx = blockIdx.x * 2 + (threadIdx.x >> 7);
    if (idx >= n_rows) return;
    int f = threadIdx.x & 127;
    int b = batch[idx];
    float v = H[(size_t)idx * 128 + f] * sc[f] + sc[128 + f];
    unsafeAtomicAdd(&g[(size_t)b * 128 + f], v);
}

// ---------------- head: out = relu(g@Wf1+bf1)@Wf2 + bf2 ---------------------
__global__ __launch_bounds__(256) void k_head(const float* __restrict__ g,
                                              const float* __restrict__ Wf1,
                                              const float* __restrict__ bf1,
                                              const float* __restrict__ Wf2,
                                              const float* __restrict__ bf2,
                                              float* __restrict__ out)
{
    __shared__ float sg[128];
    __shared__ float sh[256];
    int t = threadIdx.x;
    int G = blockIdx.x;
    if (t < 128) sg[t] = g[(size_t)G * 128 + t];
    __syncthreads();
    float a = bf1[t];
    #pragma unroll 8
    for (int k = 0; k < 128; ++k) a = fmaf(sg[k], Wf1[k * 256 + t], a);
    sh[t] = fmaxf(a, 0.f);
    __syncthreads();
    if (t < 192) {
        int o = t >> 4, l = t & 15;
        float p = 0.f;
        for (int k = l; k < 256; k += 16) p += sh[k] * Wf2[k * 12 + o];
        #pragma unroll
        for (int m = 8; m >= 1; m >>= 1) p += __shfl_xor(p, m, 16);
        if (l == 0) out[(size_t)G * 12 + o] = p + bf2[o];
    }
}

extern "C" void kernel_launch(void* const* d_in, const int* in_sizes, int n_in,
                              void* d_out, int out_size, void* d_ws, size_t ws_size,
                              hipStream_t stream)
{
    const float* x     = (const float*)d_in[0];
    const int*   ei    = (const int*)d_in[1];
    const int*   batch = (const int*)d_in[2];
    const float* W1    = (const float*)d_in[3];
    const float* b1    = (const float*)d_in[4];
    const float* W2    = (const float*)d_in[5];
    const float* b2    = (const float*)d_in[6];
    const float* gamma = (const float*)d_in[7];
    const float* beta  = (const float*)d_in[8];
    const float* Wf1   = (const float*)d_in[9];
    const float* bf1   = (const float*)d_in[10];
    const float* Wf2   = (const float*)d_in[11];
    const float* bf2   = (const float*)d_in[12];

    int n_nodes = in_sizes[0] / N_FEAT;
    int n_edges = in_sizes[1] / 2;
    const int* src = ei;
    const int* dst = ei + n_edges;

    char* ws = (char*)d_ws;
    size_t planeBytes = (size_t)n_nodes * N_FEAT * sizeof(unsigned short);  // bf16 plane
    size_t nodeBytes  = (size_t)n_nodes * N_FEAT * sizeof(float);
    size_t gBytes     = (size_t)N_GRAPHS * N_FEAT * sizeof(float);

    unsigned short* Ahi = (unsigned short*)ws;
    unsigned short* Alo = (unsigned short*)(ws + planeBytes);
    float* H     = (float*)(ws + 2 * planeBytes);
    float* g     = (float*)(ws + 2 * planeBytes + nodeBytes);
    float* stats = (float*)((char*)g + gBytes);
    float* sc    = stats + 256;
    unsigned short* Wt1 = (unsigned short*)(sc + 256);
    unsigned short* Wt2 = Wt1 + 128 * 128;
    char* p = (char*)(Wt2 + 128 * 128);
    int nb = (n_nodes + 255) / 256;
    int* counts    = (int*)p;  p += (size_t)n_nodes * sizeof(int);
    int* row_start = (int*)p;  p += (size_t)(n_nodes + 1) * sizeof(int);
    int* cursor    = (int*)p;  p += (size_t)n_nodes * sizeof(int);
    int* bsum      = (int*)p;  p += 256 * sizeof(int);
    int* boff      = (int*)p;  p += 256 * sizeof(int);
    int* csr       = (int*)p;  // [n_edges]

    hipMemsetAsync(g, 0, gBytes + 512 * sizeof(float), stream);
    hipMemsetAsync(counts, 0, (size_t)n_nodes * sizeof(int), stream);

    // ---- weight prep + CSR build ----
    k_cvtW<<<128, 256, 0, stream>>>(W1, W2, Wt1, Wt2);
    int eb = (n_edges + 255) / 256;
    k_hist<<<eb, 256, 0, stream>>>(dst, counts, n_edges);
    k_bsum<<<nb, 256, 0, stream>>>(counts, bsum, n_nodes);
    k_bscan<<<1, 256, 0, stream>>>(bsum, boff, nb);
    k_apply<<<nb, 256, 0, stream>>>(counts, boff, row_start, cursor, n_nodes);
    k_fill<<<eb, 256, 0, stream>>>(src, dst, cursor, csr, n_edges);

    // ---- pull aggregation (includes +x), split-bf16 output ----
    k_gather<<<(n_nodes + 3) / 4, 256, 0, stream>>>(x, csr, row_start, Ahi, Alo, n_nodes);

    // ---- MFMA MLP ----
    k_mlp1_mfma<<<(n_nodes + 63) / 64, 256, 0, stream>>>(Ahi, Alo, Wt1, b1, Wt2, b2, H, n_nodes);

    // ---- BN + pool + head ----
    k_bnstats<<<784, 128, 0, stream>>>(H, stats, n_nodes);
    k_bnfin<<<1, 128, 0, stream>>>(stats, gamma, beta, sc, n_nodes);
    k_pool<<<(n_nodes + 1) / 2, 256, 0, stream>>>(H, batch, sc, g, n_nodes);
    k_head<<<N_GRAPHS, 256, 0, stream>>>(g, Wf1, bf1, Wf2, bf2, (float*)d_out);
}

// Round 5
// 228.785 us; speedup vs baseline: 6.6002x; 1.1220x over previous
//
#include <hip/hip_runtime.h>

#define N_FEAT   128
#define N_GRAPHS 2048
#define BN_EPS   1e-5f
#define LDA      136   // padded LDS row length (bf16 elems): +8 pad -> 2-way bank alias (free)

typedef __attribute__((ext_vector_type(8))) short  bf16x8;
typedef __attribute__((ext_vector_type(4))) float  f32x4;

__device__ __forceinline__ unsigned short f2bf(float f) {
    union { float f; unsigned int u; } c; c.f = f;
    unsigned int r = c.u + 0x7fffu + ((c.u >> 16) & 1u);   // RNE
    return (unsigned short)(r >> 16);
}
__device__ __forceinline__ float bf2f(unsigned short h) {
    union { unsigned int u; float f; } c; c.u = ((unsigned int)h) << 16;
    return c.f;
}

// ---------------- x -> bf16 plane -------------------------------------------
__global__ __launch_bounds__(256) void k_cvtx(const float* __restrict__ x,
                                              unsigned short* __restrict__ xb,
                                              int n8)   // total elems / 8
{
    int i = blockIdx.x * 256 + threadIdx.x;
    if (i >= n8) return;
    float4 a = ((const float4*)x)[i * 2];
    float4 b = ((const float4*)x)[i * 2 + 1];
    ushort4 u0, u1;
    u0.x = f2bf(a.x); u0.y = f2bf(a.y); u0.z = f2bf(a.z); u0.w = f2bf(a.w);
    u1.x = f2bf(b.x); u1.y = f2bf(b.y); u1.z = f2bf(b.z); u1.w = f2bf(b.w);
    ((ushort4*)xb)[i * 2]     = u0;
    ((ushort4*)xb)[i * 2 + 1] = u1;
}

// ---------------- CSR build: histogram of dst -------------------------------
__global__ __launch_bounds__(256) void k_hist(const int* __restrict__ dst,
                                              int* __restrict__ counts,
                                              int n_edges)
{
    int e = blockIdx.x * 256 + threadIdx.x;
    if (e < n_edges) atomicAdd(&counts[dst[e]], 1);
}

// ---------------- hierarchical exclusive scan over counts -------------------
__global__ __launch_bounds__(256) void k_bsum(const int* __restrict__ counts,
                                              int* __restrict__ bsum, int n)
{
    __shared__ int s[256];
    int t = threadIdx.x;
    int i = blockIdx.x * 256 + t;
    s[t] = (i < n) ? counts[i] : 0;
    __syncthreads();
    for (int o = 128; o > 0; o >>= 1) {
        if (t < o) s[t] += s[t + o];
        __syncthreads();
    }
    if (t == 0) bsum[blockIdx.x] = s[0];
}

__global__ __launch_bounds__(256) void k_bscan(const int* __restrict__ bsum,
                                               int* __restrict__ boff, int nb)
{
    __shared__ int s[256];
    int t = threadIdx.x;
    int v = (t < nb) ? bsum[t] : 0;
    s[t] = v;
    __syncthreads();
    for (int o = 1; o < 256; o <<= 1) {
        int u = (t >= o) ? s[t - o] : 0;
        __syncthreads();
        s[t] += u;
        __syncthreads();
    }
    boff[t] = s[t] - v;   // exclusive
}

__global__ __launch_bounds__(256) void k_apply(const int* __restrict__ counts,
                                               const int* __restrict__ boff,
                                               int* __restrict__ row_start,
                                               int* __restrict__ cursor, int n)
{
    __shared__ int s[256];
    int t = threadIdx.x;
    int i = blockIdx.x * 256 + t;
    int c = (i < n) ? counts[i] : 0;
    s[t] = c;
    __syncthreads();
    for (int o = 1; o < 256; o <<= 1) {
        int u = (t >= o) ? s[t - o] : 0;
        __syncthreads();
        s[t] += u;
        __syncthreads();
    }
    int excl = boff[blockIdx.x] + s[t] - c;
    if (i < n) {
        row_start[i] = excl;
        cursor[i] = excl;
        if (i == n - 1) row_start[n] = excl + c;
    }
}

// ---------------- CSR build: fill adjacency ---------------------------------
__global__ __launch_bounds__(256) void k_fill(const int* __restrict__ src,
                                              const int* __restrict__ dst,
                                              int* __restrict__ cursor,
                                              int* __restrict__ csr,
                                              int n_edges)
{
    int e = blockIdx.x * 256 + threadIdx.x;
    if (e < n_edges) {
        int slot = atomicAdd(&cursor[dst[e]], 1);
        csr[slot] = src[e];
    }
}

// ---------------- weight prep: Wt[c][k] = bf16(W[k][c]) ---------------------
__global__ __launch_bounds__(256) void k_cvtW(const float* __restrict__ W1,
                                              const float* __restrict__ W2,
                                              unsigned short* __restrict__ Wt1,
                                              unsigned short* __restrict__ Wt2)
{
    int i = blockIdx.x * 256 + threadIdx.x;   // 0..32767
    int which = i >> 14;
    int k = (i >> 7) & 127;
    int c = i & 127;
    const float* W = which ? W2 : W1;
    unsigned short* O = which ? Wt2 : Wt1;
    O[c * 128 + k] = f2bf(W[k * 128 + c]);
}

// ---------------- pull aggregation (bf16 neighbors, f32 self) ---------------
// one node per wave; half-waves own edges j / j+1; lane handles 4 features
__global__ __launch_bounds__(256) void k_gather(const float* __restrict__ x,
                                                const unsigned short* __restrict__ xb,
                                                const int* __restrict__ csr,
                                                const int* __restrict__ row_start,
                                                unsigned short* __restrict__ Ahi,
                                                unsigned short* __restrict__ Alo,
                                                int n_nodes)
{
    int node = blockIdx.x * 4 + (threadIdx.x >> 6);
    if (node >= n_nodes) return;
    int l = threadIdx.x & 63;
    int h = l >> 5;          // edge-pair slot
    int lh = l & 31;         // feature group lh*4..lh*4+3
    int beg = row_start[node], end = row_start[node + 1];
    float4 v = make_float4(0.f, 0.f, 0.f, 0.f);
    for (int j = beg + h; j < end; j += 2) {
        int s = csr[j];
        ushort4 u = *(const ushort4*)(xb + (size_t)s * 128 + lh * 4);
        v.x += bf2f(u.x); v.y += bf2f(u.y); v.z += bf2f(u.z); v.w += bf2f(u.w);
    }
    v.x += __shfl_xor(v.x, 32);
    v.y += __shfl_xor(v.y, 32);
    v.z += __shfl_xor(v.z, 32);
    v.w += __shfl_xor(v.w, 32);
    if (h == 0) {
        float4 xs = ((const float4*)(x + (size_t)node * 128))[lh];
        v.x += xs.x; v.y += xs.y; v.z += xs.z; v.w += xs.w;
        ushort4 hi, lo;
        hi.x = f2bf(v.x); lo.x = f2bf(v.x - bf2f(hi.x));
        hi.y = f2bf(v.y); lo.y = f2bf(v.y - bf2f(hi.y));
        hi.z = f2bf(v.z); lo.z = f2bf(v.z - bf2f(hi.z));
        hi.w = f2bf(v.w); lo.w = f2bf(v.w - bf2f(hi.w));
        *(ushort4*)(Ahi + (size_t)node * 128 + lh * 4) = hi;
        *(ushort4*)(Alo + (size_t)node * 128 + lh * 4) = lo;
    }
}

// ---------------- fused MLP1 via MFMA + BN-stat partials --------------------
__global__ __launch_bounds__(256) void k_mlp1_mfma(const unsigned short* __restrict__ Ahi,
                                                   const unsigned short* __restrict__ Alo,
                                                   const unsigned short* __restrict__ Wt1,
                                                   const float* __restrict__ b1,
                                                   const unsigned short* __restrict__ Wt2,
                                                   const float* __restrict__ b2,
                                                   float* __restrict__ H,
                                                   float* __restrict__ partial,
                                                   int n_rows)
{
    __shared__ unsigned short sHi[64 * LDA];
    __shared__ unsigned short sLo[64 * LDA];
    int t = threadIdx.x;
    int wave = t >> 6, l = t & 63;
    int lr = l & 15;        // row-part (A) / col-part (B,D)
    int lk = l >> 4;        // k-group 0..3
    int row0 = blockIdx.x * 64;
    int col0 = wave * 32;

    // stage A hi/lo tile: 64 rows x 128 bf16 per plane
    #pragma unroll
    for (int it = 0; it < 4; ++it) {
        int idx = it * 256 + t;          // 0..1023
        int r = idx >> 4, c8 = idx & 15;
        int gr = row0 + r;
        int4 vh = make_int4(0, 0, 0, 0), vl = make_int4(0, 0, 0, 0);
        if (gr < n_rows) {
            vh = ((const int4*)(Ahi + (size_t)gr * 128))[c8];
            vl = ((const int4*)(Alo + (size_t)gr * 128))[c8];
        }
        *(int4*)&sHi[r * LDA + c8 * 8] = vh;
        *(int4*)&sLo[r * LDA + c8 * 8] = vl;
    }
    __syncthreads();

    f32x4 acc[4][2];
    #pragma unroll
    for (int m = 0; m < 4; ++m)
        #pragma unroll
        for (int n = 0; n < 2; ++n) acc[m][n] = (f32x4){0.f, 0.f, 0.f, 0.f};

    // ---- layer 1: acc = A @ W1 ----
    #pragma unroll
    for (int ks = 0; ks < 4; ++ks) {
        bf16x8 bfrag[2];
        #pragma unroll
        for (int n = 0; n < 2; ++n) {
            int c = col0 + n * 16 + lr;
            bfrag[n] = *(const bf16x8*)(Wt1 + (size_t)c * 128 + ks * 32 + lk * 8);
        }
        #pragma unroll
        for (int m = 0; m < 4; ++m) {
            bf16x8 ah = *(const bf16x8*)&sHi[(m * 16 + lr) * LDA + ks * 32 + lk * 8];
            bf16x8 al = *(const bf16x8*)&sLo[(m * 16 + lr) * LDA + ks * 32 + lk * 8];
            #pragma unroll
            for (int n = 0; n < 2; ++n) {
                acc[m][n] = __builtin_amdgcn_mfma_f32_16x16x32_bf16(ah, bfrag[n], acc[m][n], 0, 0, 0);
                acc[m][n] = __builtin_amdgcn_mfma_f32_16x16x32_bf16(al, bfrag[n], acc[m][n], 0, 0, 0);
            }
        }
    }
    __syncthreads();   // all waves done reading A tiles

    // ---- T1 = relu(acc + b1), split hi/lo back into sHi/sLo ----
    #pragma unroll
    for (int n = 0; n < 2; ++n) {
        int c = col0 + n * 16 + lr;
        float bb = b1[c];
        #pragma unroll
        for (int m = 0; m < 4; ++m) {
            #pragma unroll
            for (int i = 0; i < 4; ++i) {
                int r = m * 16 + lk * 4 + i;
                float v = fmaxf(acc[m][n][i] + bb, 0.f);
                unsigned short hb = f2bf(v);
                sHi[r * LDA + c] = hb;
                sLo[r * LDA + c] = f2bf(v - bf2f(hb));
            }
        }
    }
    __syncthreads();

    #pragma unroll
    for (int m = 0; m < 4; ++m)
        #pragma unroll
        for (int n = 0; n < 2; ++n) acc[m][n] = (f32x4){0.f, 0.f, 0.f, 0.f};

    // ---- layer 2: acc = T1 @ W2 ----
    #pragma unroll
    for (int ks = 0; ks < 4; ++ks) {
        bf16x8 bfrag[2];
        #pragma unroll
        for (int n = 0; n < 2; ++n) {
            int c = col0 + n * 16 + lr;
            bfrag[n] = *(const bf16x8*)(Wt2 + (size_t)c * 128 + ks * 32 + lk * 8);
        }
        #pragma unroll
        for (int m = 0; m < 4; ++m) {
            bf16x8 ah = *(const bf16x8*)&sHi[(m * 16 + lr) * LDA + ks * 32 + lk * 8];
            bf16x8 al = *(const bf16x8*)&sLo[(m * 16 + lr) * LDA + ks * 32 + lk * 8];
            #pragma unroll
            for (int n = 0; n < 2; ++n) {
                acc[m][n] = __builtin_amdgcn_mfma_f32_16x16x32_bf16(ah, bfrag[n], acc[m][n], 0, 0, 0);
                acc[m][n] = __builtin_amdgcn_mfma_f32_16x16x32_bf16(al, bfrag[n], acc[m][n], 0, 0, 0);
            }
        }
    }

    // ---- H = relu(acc + b2) + per-block BN partial sums ----
    float ps[2] = {0.f, 0.f}, pq[2] = {0.f, 0.f};
    #pragma unroll
    for (int n = 0; n < 2; ++n) {
        int c = col0 + n * 16 + lr;
        float bb = b2[c];
        #pragma unroll
        for (int m = 0; m < 4; ++m) {
            #pragma unroll
            for (int i = 0; i < 4; ++i) {
                int gr = row0 + m * 16 + lk * 4 + i;
                float v = fmaxf(acc[m][n][i] + bb, 0.f);
                if (gr < n_rows) {
                    H[(size_t)gr * 128 + c] = v;
                    ps[n] += v;
                    pq[n] += v * v;
                }
            }
        }
    }
    // reduce over lk groups (lanes xor 16, 32 share the same column)
    #pragma unroll
    for (int n = 0; n < 2; ++n) {
        ps[n] += __shfl_xor(ps[n], 16); ps[n] += __shfl_xor(ps[n], 32);
        pq[n] += __shfl_xor(pq[n], 16); pq[n] += __shfl_xor(pq[n], 32);
    }
    if (lk == 0) {
        #pragma unroll
        for (int n = 0; n < 2; ++n) {
            int c = col0 + n * 16 + lr;
            partial[(size_t)blockIdx.x * 256 + c]       = ps[n];
            partial[(size_t)blockIdx.x * 256 + 128 + c] = pq[n];
        }
    }
}

// ---------------- reduce BN partials ----------------------------------------
__global__ __launch_bounds__(256) void k_bnred(const float* __restrict__ partial,
                                               float* __restrict__ stats, int nblk)
{
    int j = threadIdx.x;
    float s = 0.f;
    for (int b = blockIdx.x; b < nblk; b += gridDim.x)
        s += partial[(size_t)b * 256 + j];
    unsafeAtomicAdd(&stats[j], s);
}

__global__ void k_bnfin(const float* __restrict__ stats,
                        const float* __restrict__ gamma,
                        const float* __restrict__ beta,
                        float* __restrict__ sc, int n_rows)
{
    int f = threadIdx.x;   // 128 threads
    float inv_n = 1.0f / (float)n_rows;
    float mean = stats[f] * inv_n;
    float var = stats[128 + f] * inv_n - mean * mean;
    float inv = rsqrtf(var + BN_EPS);
    float scale = gamma[f] * inv;
    sc[f] = scale;
    sc[128 + f] = beta[f] - mean * scale;
}

// ---------------- pool: g[batch[n]] += H[n]*scale + shift -------------------
__global__ __launch_bounds__(256) void k_pool(const float* __restrict__ H,
                                              const int* __restrict__ batch,
                                              const float* __restrict__ sc,
                                              float* __restrict__ g,
                                              int n_rows)
{
    int idx = blockIdx.x * 2 + (threadIdx.x >> 7);
    if (idx >= n_rows) return;
    int f = threadIdx.x & 127;
    int b = batch[idx];
    float v = H[(size_t)idx * 128 + f] * sc[f] + sc[128 + f];
    unsafeAtomicAdd(&g[(size_t)b * 128 + f], v);
}

// ---------------- head: out = relu(g@Wf1+bf1)@Wf2 + bf2 ---------------------
__global__ __launch_bounds__(256) void k_head(const float* __restrict__ g,
                                              const float* __restrict__ Wf1,
                                              const float* __restrict__ bf1,
                                              const float* __restrict__ Wf2,
                                              const float* __restrict__ bf2,
                                              float* __restrict__ out)
{
    __shared__ float sg[128];
    __shared__ float sh[256];
    int t = threadIdx.x;
    int G = blockIdx.x;
    if (t < 128) sg[t] = g[(size_t)G * 128 + t];
    __syncthreads();
    float a = bf1[t];
    #pragma unroll 8
    for (int k = 0; k < 128; ++k) a = fmaf(sg[k], Wf1[k * 256 + t], a);
    sh[t] = fmaxf(a, 0.f);
    __syncthreads();
    if (t < 192) {
        int o = t >> 4, l = t & 15;
        float p = 0.f;
        for (int k = l; k < 256; k += 16) p += sh[k] * Wf2[k * 12 + o];
        #pragma unroll
        for (int m = 8; m >= 1; m >>= 1) p += __shfl_xor(p, m, 16);
        if (l == 0) out[(size_t)G * 12 + o] = p + bf2[o];
    }
}

extern "C" void kernel_launch(void* const* d_in, const int* in_sizes, int n_in,
                              void* d_out, int out_size, void* d_ws, size_t ws_size,
                              hipStream_t stream)
{
    const float* x     = (const float*)d_in[0];
    const int*   ei    = (const int*)d_in[1];
    const int*   batch = (const int*)d_in[2];
    const float* W1    = (const float*)d_in[3];
    const float* b1    = (const float*)d_in[4];
    const float* W2    = (const float*)d_in[5];
    const float* b2    = (const float*)d_in[6];
    const float* gamma = (const float*)d_in[7];
    const float* beta  = (const float*)d_in[8];
    const float* Wf1   = (const float*)d_in[9];
    const float* bf1   = (const float*)d_in[10];
    const float* Wf2   = (const float*)d_in[11];
    const float* bf2   = (const float*)d_in[12];

    int n_nodes = in_sizes[0] / N_FEAT;
    int n_edges = in_sizes[1] / 2;
    const int* src = ei;
    const int* dst = ei + n_edges;

    char* ws = (char*)d_ws;
    size_t planeBytes = (size_t)n_nodes * N_FEAT * sizeof(unsigned short);  // bf16 plane
    size_t nodeBytes  = (size_t)n_nodes * N_FEAT * sizeof(float);
    size_t gBytes     = (size_t)N_GRAPHS * N_FEAT * sizeof(float);
    int nblk_m = (n_nodes + 63) / 64;   // mlp1 blocks

    unsigned short* Ahi = (unsigned short*)ws;
    unsigned short* Alo = (unsigned short*)(ws + planeBytes);
    // xb and H share this region: xb dead before mlp1 writes H
    unsigned short* xb  = (unsigned short*)(ws + 2 * planeBytes);
    float* H     = (float*)(ws + 2 * planeBytes);
    float* g     = (float*)(ws + 2 * planeBytes + nodeBytes);
    float* stats = (float*)((char*)g + gBytes);
    float* sc    = stats + 256;
    unsigned short* Wt1 = (unsigned short*)(sc + 256);
    unsigned short* Wt2 = Wt1 + 128 * 128;
    float* partial = (float*)(Wt2 + 128 * 128);          // [nblk_m][256]
    char* p = (char*)(partial + (size_t)nblk_m * 256);
    int nb = (n_nodes + 255) / 256;
    int* counts    = (int*)p;  p += (size_t)n_nodes * sizeof(int);
    int* row_start = (int*)p;  p += (size_t)(n_nodes + 1) * sizeof(int);
    int* cursor    = (int*)p;  p += (size_t)n_nodes * sizeof(int);
    int* bsum      = (int*)p;  p += 256 * sizeof(int);
    int* boff      = (int*)p;  p += 256 * sizeof(int);
    int* csr       = (int*)p;  // [n_edges]

    hipMemsetAsync(g, 0, gBytes + 512 * sizeof(float), stream);
    hipMemsetAsync(counts, 0, (size_t)n_nodes * sizeof(int), stream);

    // ---- conversions + CSR build ----
    int n8 = n_nodes * N_FEAT / 8;
    k_cvtx<<<(n8 + 255) / 256, 256, 0, stream>>>(x, xb, n8);
    k_cvtW<<<128, 256, 0, stream>>>(W1, W2, Wt1, Wt2);
    int eb = (n_edges + 255) / 256;
    k_hist<<<eb, 256, 0, stream>>>(dst, counts, n_edges);
    k_bsum<<<nb, 256, 0, stream>>>(counts, bsum, n_nodes);
    k_bscan<<<1, 256, 0, stream>>>(bsum, boff, nb);
    k_apply<<<nb, 256, 0, stream>>>(counts, boff, row_start, cursor, n_nodes);
    k_fill<<<eb, 256, 0, stream>>>(src, dst, cursor, csr, n_edges);

    // ---- pull aggregation (bf16 neighbors + exact self) ----
    k_gather<<<(n_nodes + 3) / 4, 256, 0, stream>>>(x, xb, csr, row_start, Ahi, Alo, n_nodes);

    // ---- MFMA MLP (+ BN partials) ----
    k_mlp1_mfma<<<nblk_m, 256, 0, stream>>>(Ahi, Alo, Wt1, b1, Wt2, b2, H, partial, n_nodes);

    // ---- BN finalize + pool + head ----
    k_bnred<<<64, 256, 0, stream>>>(partial, stats, nblk_m);
    k_bnfin<<<1, 128, 0, stream>>>(stats, gamma, beta, sc, n_nodes);
    k_pool<<<(n_nodes + 1) / 2, 256, 0, stream>>>(H, batch, sc, g, n_nodes);
    k_head<<<N_GRAPHS, 256, 0, stream>>>(g, Wf1, bf1, Wf2, bf2, (float*)d_out);
}